// Round 12
// baseline (99.358 us; speedup 1.0000x reference)
//
#include <hip/hip_runtime.h>

#define TLEN 512
#define LOG2E 1.44269504088896340736f

#if __has_builtin(__builtin_amdgcn_exp2f)
#define EXP2F(x) __builtin_amdgcn_exp2f(x)
#else
#define EXP2F(x) __exp2f(x)
#endif
#if __has_builtin(__builtin_amdgcn_rcpf)
#define RCPF(x) __builtin_amdgcn_rcpf(x)
#else
#define RCPF(x) (1.0f / (x))
#endif

// ds_swizzle BitMode xor (epilogue MLP head only, off the hot loop)
#define SWZ(v, xm) __int_as_float(__builtin_amdgcn_ds_swizzle(__float_as_int(v), (((xm) << 10) | 0x1F)))
// Generic DPP: dst = src[permuted lane], all lanes valid
#define DPPF(v, ctrl) __int_as_float(__builtin_amdgcn_update_dpp(__float_as_int(v), __float_as_int(v), (ctrl), 0xF, 0xF, false))
// quad_perm broadcast of quad-lane k
#define QB(v, k) DPPF(v, 0x55 * (k))
// Direction-free lane exchanges within a row of 16 (verified R1-R11, absmax 0):
#define XOR3(v)  DPPF(v, 0x1B)   // quad_perm [3,2,1,0]
#define XOR7(v)  DPPF(v, 0x141)  // ROW_HALF_MIRROR
#define XOR8(v)  DPPF(v, 0x128)  // ROW_ROR:8

struct X4 { float4 a, b, c, d; };   // one timestep: 16 floats, 64 B

// R12: two-phase per 32-step chunk, xd buffer in REGISTERS.
// Phase A: plain streaming block (128 independent broadcast loads + 512 FMAs
// per chunk) -- the one pattern the compiler schedules well. No LDS, no asm.
// Phase B: 32 chained STEPs consuming registers only -- the serial chain runs
// at its ~100cy/step latency floor with zero memory waits.
// One sched_barrier(0) between phases blocks exactly the bad motion (sinking
// A's dot-FMAs into B, which would put load latency back on the chain);
// cross-chunk overlap across the loop backedge stays legal.
// R8's failure was the LDS round-trip (ds_write serialization + ds_read on
// the chain), not the two-phase concept -- both are gone here.
__global__ __launch_bounds__(256)
__attribute__((amdgpu_waves_per_eu(1, 1)))
void lstm_mlp_kernel(
    const float* __restrict__ x,   // [B,512,16]
    const float* __restrict__ Wk,  // [16,16]
    const float* __restrict__ Wr,  // [4,16]
    const float* __restrict__ bg,  // [16]
    const float* __restrict__ W1,  // [4,64]
    const float* __restrict__ b1,  // [64]
    const float* __restrict__ W2,  // [64,5]
    const float* __restrict__ b2,  // [5]
    float* __restrict__ out,       // [B,5]
    int B)
{
    const int tid = blockIdx.x * 256 + threadIdx.x;
    const int seq = tid >> 4;
    if (seq >= B) return;
    const int i16 = tid & 15;
    const int j   = i16 >> 2;   // hidden unit owned by this quad
    const int q   = i16 & 3;    // gate type: 0=i, 1=f, 2=g(tanh), 3=o
    const int gate = q * 4 + j; // column in gates[16] (Keras order i,f,g,o)

    // activation pre-scale folded into weights (verified R2/R6-R11, absmax 0)
    const bool is_g = (q == 2);
    const float k1 = is_g ? (-2.0f * LOG2E) : (-LOG2E);
    const float m1c = is_g ? (-4.0f * LOG2E) : 1.0f;
    const float m0c = is_g ? (2.0f * LOG2E) : 0.0f;

    float wk[16];
#pragma unroll
    for (int f = 0; f < 16; ++f) wk[f] = k1 * Wk[f * 16 + gate];
    const float wr0 = k1 * Wr[(j ^ 0) * 16 + gate];
    const float wr1 = k1 * Wr[(j ^ 1) * 16 + gate];
    const float wr2 = k1 * Wr[(j ^ 2) * 16 + gate];
    const float wr3 = k1 * Wr[(j ^ 3) * 16 + gate];
    const float biasS = k1 * bg[gate];

    const X4* xt = reinterpret_cast<const X4*>(x) + (size_t)seq * TLEN;

    float cs = 0.0f, h = 0.0f;   // cs = -2*log2e * c

#define DOT4S(v, w0_, w1_, w2_, w3_, seed) \
    fmaf((v).x, (w0_), fmaf((v).y, (w1_), fmaf((v).z, (w2_), fmaf((v).w, (w3_), (seed)))))
#define DOTB(Bk) \
    ((DOT4S((Bk).a, wk[0], wk[1], wk[2], wk[3], biasS) + \
      DOT4S((Bk).b, wk[4], wk[5], wk[6], wk[7], 0.0f)) + \
     (DOT4S((Bk).c, wk[8], wk[9], wk[10], wk[11], 0.0f) + \
      DOT4S((Bk).d, wk[12], wk[13], wk[14], wk[15], 0.0f)))

// tree-shaped preactivation sum, then the LSTM cell update (verified R8-R11)
#define STEP(XD) { \
    float h1_ = XOR7(XOR3(h));   /* h[j^1] */ \
    float h2_ = XOR8(h);         /* h[j^2] */ \
    float h3_ = XOR8(h1_);       /* h[j^3] */ \
    float preA = fmaf(h, wr0, fmaf(h1_, wr1, (XD))); \
    float preB = fmaf(h2_, wr2, h3_ * wr3); \
    float pre = preA + preB; \
    float r_ = RCPF(1.0f + EXP2F(pre)); \
    float av = fmaf(m1c, r_, m0c); \
    float iv = QB(av, 0); \
    float fv = QB(av, 1); \
    float gv = QB(av, 2); \
    float ov = QB(av, 3); \
    cs = fmaf(fv, cs, iv * gv); \
    float th_ = fmaf(2.0f, RCPF(1.0f + EXP2F(cs)), -1.0f); \
    h = ov * th_; }

    // chunked two-phase main loop: 16 chunks x 32 steps
#pragma clang loop unroll(disable)
    for (int c = 0; c < 16; ++c) {
        const X4* xc = xt + c * 32;
        float xd[32];   // fully-static indices after unroll -> 32 VGPRs

        // ---- Phase A: streaming dot block (no dependencies between t) ----
#pragma unroll
        for (int t = 0; t < 32; ++t) {
            X4 v = xc[t];
            xd[t] = DOTB(v);
        }

        // fence: A's FMAs may not sink into B (would put load latency back
        // on the chain). Cross-chunk motion over the backedge stays legal.
        __builtin_amdgcn_sched_barrier(0);

        // ---- Phase B: pure-register recurrence ----
#pragma unroll
        for (int t = 0; t < 32; ++t) {
            STEP(xd[t]);
        }
    }

    // ---- MLP head (runs once; verified R2/R6-R11) ----
    float hA = h;
    float hB = SWZ(h, 4), hC = SWZ(h, 8), hD = SWZ(h, 12);

    float p0 = 0.f, p1 = 0.f, p2 = 0.f, p3 = 0.f, p4 = 0.f;
#pragma unroll
    for (int r = 0; r < 4; ++r) {
        const int u = i16 * 4 + r;            // hidden unit of layer 1, 4 per lane
        float acc = b1[u];
        acc = fmaf(hA, W1[(j ^ 0) * 64 + u], acc);
        acc = fmaf(hB, W1[(j ^ 1) * 64 + u], acc);
        acc = fmaf(hC, W1[(j ^ 2) * 64 + u], acc);
        acc = fmaf(hD, W1[(j ^ 3) * 64 + u], acc);
        acc = fmaxf(acc, 0.0f);
        p0 = fmaf(acc, W2[u * 5 + 0], p0);
        p1 = fmaf(acc, W2[u * 5 + 1], p1);
        p2 = fmaf(acc, W2[u * 5 + 2], p2);
        p3 = fmaf(acc, W2[u * 5 + 3], p3);
        p4 = fmaf(acc, W2[u * 5 + 4], p4);
    }
    // butterfly all-reduce across the 16-lane group
    p0 += SWZ(p0, 1); p1 += SWZ(p1, 1); p2 += SWZ(p2, 1); p3 += SWZ(p3, 1); p4 += SWZ(p4, 1);
    p0 += SWZ(p0, 2); p1 += SWZ(p1, 2); p2 += SWZ(p2, 2); p3 += SWZ(p3, 2); p4 += SWZ(p4, 2);
    p0 += SWZ(p0, 4); p1 += SWZ(p1, 4); p2 += SWZ(p2, 4); p3 += SWZ(p3, 4); p4 += SWZ(p4, 4);
    p0 += SWZ(p0, 8); p1 += SWZ(p1, 8); p2 += SWZ(p2, 8); p3 += SWZ(p3, 8); p4 += SWZ(p4, 8);

    p0 += b2[0]; p1 += b2[1]; p2 += b2[2]; p3 += b2[3]; p4 += b2[4];

    float mx = fmaxf(fmaxf(fmaxf(p0, p1), fmaxf(p2, p3)), p4);
    float e0 = EXP2F((p0 - mx) * LOG2E);
    float e1 = EXP2F((p1 - mx) * LOG2E);
    float e2 = EXP2F((p2 - mx) * LOG2E);
    float e3 = EXP2F((p3 - mx) * LOG2E);
    float e4 = EXP2F((p4 - mx) * LOG2E);
    float s = ((e0 + e1) + (e2 + e3)) + e4;
    float rs = RCPF(s);

    if (i16 == 0) {
        float* op = out + (size_t)seq * 5;
        op[0] = e0 * rs; op[1] = e1 * rs; op[2] = e2 * rs;
        op[3] = e3 * rs; op[4] = e4 * rs;
    }
}

extern "C" void kernel_launch(void* const* d_in, const int* in_sizes, int n_in,
                              void* d_out, int out_size, void* d_ws, size_t ws_size,
                              hipStream_t stream) {
    const float* x  = (const float*)d_in[0];
    const float* Wk = (const float*)d_in[1];
    const float* Wr = (const float*)d_in[2];
    const float* bg = (const float*)d_in[3];
    const float* W1 = (const float*)d_in[4];
    const float* b1 = (const float*)d_in[5];
    const float* W2 = (const float*)d_in[6];
    const float* b2 = (const float*)d_in[7];
    float* out = (float*)d_out;

    const int B = in_sizes[0] / (TLEN * 16);   // 4096
    const int threads = B * 16;
    dim3 block(256);
    dim3 grid((threads + 255) / 256);
    lstm_mlp_kernel<<<grid, block, 0, stream>>>(x, Wk, Wr, bg, W1, b1, W2, b2, out, B);
}

// Round 13
// 83.057 us; speedup vs baseline: 1.1963x; 1.1963x over previous
//
#include <hip/hip_runtime.h>

#define TLEN 512
#define LOG2E 1.44269504088896340736f

#if __has_builtin(__builtin_amdgcn_exp2f)
#define EXP2F(x) __builtin_amdgcn_exp2f(x)
#else
#define EXP2F(x) __exp2f(x)
#endif
#if __has_builtin(__builtin_amdgcn_rcpf)
#define RCPF(x) __builtin_amdgcn_rcpf(x)
#else
#define RCPF(x) (1.0f / (x))
#endif

// ds_swizzle BitMode xor (epilogue MLP head only, off the hot loop)
#define SWZ(v, xm) __int_as_float(__builtin_amdgcn_ds_swizzle(__float_as_int(v), (((xm) << 10) | 0x1F)))
// Generic DPP: dst = src[permuted lane], all lanes valid
#define DPPF(v, ctrl) __int_as_float(__builtin_amdgcn_update_dpp(__float_as_int(v), __float_as_int(v), (ctrl), 0xF, 0xF, false))
// quad_perm broadcast of quad-lane k
#define QB(v, k) DPPF(v, 0x55 * (k))
// Direction-free lane exchanges within a row of 16 (verified R1-R12, absmax 0):
#define XOR3(v)  DPPF(v, 0x1B)   // quad_perm [3,2,1,0]
#define XOR7(v)  DPPF(v, 0x141)  // ROW_HALF_MIRROR
#define XOR8(v)  DPPF(v, 0x128)  // ROW_ROR:8

struct X4 { float4 a, b, c, d; };   // one timestep: 16 floats, 64 B

// sched_group_barrier: emit exactly N insts of class MASK at this point.
// Masks (LLVM SchedGroupMask): VALU=0x2, VMEM_READ=0x20.
#define SGB(mask, n) __builtin_amdgcn_sched_group_barrier((mask), (n), 0)

// R13: the 12-round diagnosis is that the PRE-RA SCHEDULER sinks every
// prefetch load to ~2 steps before use (VGPR pinned at 132 across four
// different structures), leaving ~900cy HBM latency exposed per step.
// Fix: force emission order with sched_group_barrier. 9-slot ring makes the
// per-body load target DEAD (consumed last body) -> no WAR against the dot,
// so [4x VMEM_READ][46x VALU] per body is a legal forced schedule with
// >= 8-body in-flight distance. RA must then keep 144 ring regs live.
__global__ __launch_bounds__(256)
__attribute__((amdgpu_waves_per_eu(1, 1)))
void lstm_mlp_kernel(
    const float* __restrict__ x,   // [B,512,16]
    const float* __restrict__ Wk,  // [16,16]
    const float* __restrict__ Wr,  // [4,16]
    const float* __restrict__ bg,  // [16]
    const float* __restrict__ W1,  // [4,64]
    const float* __restrict__ b1,  // [64]
    const float* __restrict__ W2,  // [64,5]
    const float* __restrict__ b2,  // [5]
    float* __restrict__ out,       // [B,5]
    int B)
{
    const int tid = blockIdx.x * 256 + threadIdx.x;
    const int seq = tid >> 4;
    if (seq >= B) return;
    const int i16 = tid & 15;
    const int j   = i16 >> 2;   // hidden unit owned by this quad
    const int q   = i16 & 3;    // gate type: 0=i, 1=f, 2=g(tanh), 3=o
    const int gate = q * 4 + j; // column in gates[16] (Keras order i,f,g,o)

    // activation pre-scale folded into weights (verified R2/R6-R12, absmax 0)
    const bool is_g = (q == 2);
    const float k1 = is_g ? (-2.0f * LOG2E) : (-LOG2E);
    const float m1c = is_g ? (-4.0f * LOG2E) : 1.0f;
    const float m0c = is_g ? (2.0f * LOG2E) : 0.0f;

    float wk[16];
#pragma unroll
    for (int f = 0; f < 16; ++f) wk[f] = k1 * Wk[f * 16 + gate];
    const float wr0 = k1 * Wr[(j ^ 0) * 16 + gate];
    const float wr1 = k1 * Wr[(j ^ 1) * 16 + gate];
    const float wr2 = k1 * Wr[(j ^ 2) * 16 + gate];
    const float wr3 = k1 * Wr[(j ^ 3) * 16 + gate];
    const float biasS = k1 * bg[gate];

    const X4* xt = reinterpret_cast<const X4*>(x) + (size_t)seq * TLEN;

    float cs = 0.0f, h = 0.0f;   // cs = -2*log2e * c

#define DOT4S(v, w0_, w1_, w2_, w3_, seed) \
    fmaf((v).x, (w0_), fmaf((v).y, (w1_), fmaf((v).z, (w2_), fmaf((v).w, (w3_), (seed)))))
#define DOTB(Bk) \
    ((DOT4S((Bk).a, wk[0], wk[1], wk[2], wk[3], biasS) + \
      DOT4S((Bk).b, wk[4], wk[5], wk[6], wk[7], 0.0f)) + \
     (DOT4S((Bk).c, wk[8], wk[9], wk[10], wk[11], 0.0f) + \
      DOT4S((Bk).d, wk[12], wk[13], wk[14], wk[15], 0.0f)))

// tree-shaped preactivation sum, then the LSTM cell update (verified R8-R12)
#define STEP(XD) { \
    float h1_ = XOR7(XOR3(h));   /* h[j^1] */ \
    float h2_ = XOR8(h);         /* h[j^2] */ \
    float h3_ = XOR8(h1_);       /* h[j^3] */ \
    float preA = fmaf(h, wr0, fmaf(h1_, wr1, (XD))); \
    float preB = fmaf(h2_, wr2, h3_ * wr3); \
    float pre = preA + preB; \
    float r_ = RCPF(1.0f + EXP2F(pre)); \
    float av = fmaf(m1c, r_, m0c); \
    float iv = QB(av, 0); \
    float fv = QB(av, 1); \
    float gv = QB(av, 2); \
    float ov = QB(av, 3); \
    cs = fmaf(fv, cs, iv * gv); \
    float th_ = fmaf(2.0f, RCPF(1.0f + EXP2F(cs)), -1.0f); \
    h = ov * th_; }

// body: load the (dead) ring slot SDST with x[TN], consume SCON, step.
// SGBs force emission: 4 VMEM_READ first, then the ~46 VALU of dot+step.
#define BODY(SDST, SCON, TN) { \
    SDST = xt[(TN)]; \
    float xd_ = DOTB(SCON); \
    STEP(xd_); \
    SGB(0x20, 4); \
    SGB(0x2, 46); }

    // 9-slot ring: x[t] lives in slot t%9. Prologue fills x[0..7] -> S0..S7.
    X4 S0 = xt[0], S1 = xt[1], S2 = xt[2], S3 = xt[3], S4 = xt[4];
    X4 S5 = xt[5], S6 = xt[6], S7 = xt[7], S8;

    // main loop: 56 iterations x 9 steps = 504; base = 9m so bodies always
    // consume S0..S8 in order and load S8,S0..S7 (x[base+8..base+16]).
    // Max load index = 495+16 = 511: no clamping, no OOB.
#pragma clang loop unroll(disable)
    for (int m = 0; m < 56; ++m) {
        const int base = m * 9;
        BODY(S8, S0, base +  8);
        BODY(S0, S1, base +  9);
        BODY(S1, S2, base + 10);
        BODY(S2, S3, base + 11);
        BODY(S3, S4, base + 12);
        BODY(S4, S5, base + 13);
        BODY(S5, S6, base + 14);
        BODY(S6, S7, base + 15);
        BODY(S7, S8, base + 16);
    }
    // tail: steps 504..511 live in S0..S7 (x[504+k] in slot (504+k)%9 = k)
    { float xd_ = DOTB(S0); STEP(xd_); }
    { float xd_ = DOTB(S1); STEP(xd_); }
    { float xd_ = DOTB(S2); STEP(xd_); }
    { float xd_ = DOTB(S3); STEP(xd_); }
    { float xd_ = DOTB(S4); STEP(xd_); }
    { float xd_ = DOTB(S5); STEP(xd_); }
    { float xd_ = DOTB(S6); STEP(xd_); }
    { float xd_ = DOTB(S7); STEP(xd_); }

    // ---- MLP head (runs once; verified R2/R6-R12) ----
    float hA = h;
    float hB = SWZ(h, 4), hC = SWZ(h, 8), hD = SWZ(h, 12);

    float p0 = 0.f, p1 = 0.f, p2 = 0.f, p3 = 0.f, p4 = 0.f;
#pragma unroll
    for (int r = 0; r < 4; ++r) {
        const int u = i16 * 4 + r;            // hidden unit of layer 1, 4 per lane
        float acc = b1[u];
        acc = fmaf(hA, W1[(j ^ 0) * 64 + u], acc);
        acc = fmaf(hB, W1[(j ^ 1) * 64 + u], acc);
        acc = fmaf(hC, W1[(j ^ 2) * 64 + u], acc);
        acc = fmaf(hD, W1[(j ^ 3) * 64 + u], acc);
        acc = fmaxf(acc, 0.0f);
        p0 = fmaf(acc, W2[u * 5 + 0], p0);
        p1 = fmaf(acc, W2[u * 5 + 1], p1);
        p2 = fmaf(acc, W2[u * 5 + 2], p2);
        p3 = fmaf(acc, W2[u * 5 + 3], p3);
        p4 = fmaf(acc, W2[u * 5 + 4], p4);
    }
    // butterfly all-reduce across the 16-lane group
    p0 += SWZ(p0, 1); p1 += SWZ(p1, 1); p2 += SWZ(p2, 1); p3 += SWZ(p3, 1); p4 += SWZ(p4, 1);
    p0 += SWZ(p0, 2); p1 += SWZ(p1, 2); p2 += SWZ(p2, 2); p3 += SWZ(p3, 2); p4 += SWZ(p4, 2);
    p0 += SWZ(p0, 4); p1 += SWZ(p1, 4); p2 += SWZ(p2, 4); p3 += SWZ(p3, 4); p4 += SWZ(p4, 4);
    p0 += SWZ(p0, 8); p1 += SWZ(p1, 8); p2 += SWZ(p2, 8); p3 += SWZ(p3, 8); p4 += SWZ(p4, 8);

    p0 += b2[0]; p1 += b2[1]; p2 += b2[2]; p3 += b2[3]; p4 += b2[4];

    float mx = fmaxf(fmaxf(fmaxf(p0, p1), fmaxf(p2, p3)), p4);
    float e0 = EXP2F((p0 - mx) * LOG2E);
    float e1 = EXP2F((p1 - mx) * LOG2E);
    float e2 = EXP2F((p2 - mx) * LOG2E);
    float e3 = EXP2F((p3 - mx) * LOG2E);
    float e4 = EXP2F((p4 - mx) * LOG2E);
    float s = ((e0 + e1) + (e2 + e3)) + e4;
    float rs = RCPF(s);

    if (i16 == 0) {
        float* op = out + (size_t)seq * 5;
        op[0] = e0 * rs; op[1] = e1 * rs; op[2] = e2 * rs;
        op[3] = e3 * rs; op[4] = e4 * rs;
    }
}

extern "C" void kernel_launch(void* const* d_in, const int* in_sizes, int n_in,
                              void* d_out, int out_size, void* d_ws, size_t ws_size,
                              hipStream_t stream) {
    const float* x  = (const float*)d_in[0];
    const float* Wk = (const float*)d_in[1];
    const float* Wr = (const float*)d_in[2];
    const float* bg = (const float*)d_in[3];
    const float* W1 = (const float*)d_in[4];
    const float* b1 = (const float*)d_in[5];
    const float* W2 = (const float*)d_in[6];
    const float* b2 = (const float*)d_in[7];
    float* out = (float*)d_out;

    const int B = in_sizes[0] / (TLEN * 16);   // 4096
    const int threads = B * 16;
    dim3 block(256);
    dim3 grid((threads + 255) / 256);
    lstm_mlp_kernel<<<grid, block, 0, stream>>>(x, Wk, Wr, bg, W1, b1, W2, b2, out, B);
}

// Round 14
// 78.662 us; speedup vs baseline: 1.2631x; 1.0559x over previous
//
#include <hip/hip_runtime.h>

#define TLEN 512
#define LOG2E 1.44269504088896340736f

#if __has_builtin(__builtin_amdgcn_exp2f)
#define EXP2F(x) __builtin_amdgcn_exp2f(x)
#else
#define EXP2F(x) __exp2f(x)
#endif
#if __has_builtin(__builtin_amdgcn_rcpf)
#define RCPF(x) __builtin_amdgcn_rcpf(x)
#else
#define RCPF(x) (1.0f / (x))
#endif

// ds_swizzle BitMode xor (epilogue MLP head only)
#define SWZ(v, xm) __int_as_float(__builtin_amdgcn_ds_swizzle(__float_as_int(v), (((xm) << 10) | 0x1F)))
// Generic DPP: dst = src[permuted lane], all lanes valid
#define DPPF(v, ctrl) __int_as_float(__builtin_amdgcn_update_dpp(__float_as_int(v), __float_as_int(v), (ctrl), 0xF, 0xF, false))
// quad_perm broadcast of quad-lane k
#define QB(v, k) DPPF(v, 0x55 * (k))
// Direction-free lane exchanges within a row of 16 (verified R1-R13, absmax 0):
#define XOR3(v)  DPPF(v, 0x1B)   // quad_perm [3,2,1,0]
#define XOR7(v)  DPPF(v, 0x141)  // ROW_HALF_MIRROR
#define XOR8(v)  DPPF(v, 0x128)  // ROW_ROR:8

// R14: producer/consumer wave specialization. 13 rounds proved the
// compiler sinks every prefetch in a single instruction stream (VGPR
// pinned at 132 across 5 structures), exposing ~300cy HBM latency on the
// serial chain. Fix the structure, not the scheduler: consumer waves'
// instruction stream has ZERO global loads (nothing to sink); producer
// waves have no chain (sinking harmless). Double-buffered LDS chunk
// pipeline with __syncthreads (wave-uniform branches, matched counts).
__global__ __launch_bounds__(512)
void lstm_mlp_kernel(
    const float* __restrict__ x,   // [B,512,16]
    const float* __restrict__ Wk,  // [16,16]
    const float* __restrict__ Wr,  // [4,16]
    const float* __restrict__ bg,  // [16]
    const float* __restrict__ W1,  // [4,64]
    const float* __restrict__ b1,  // [64]
    const float* __restrict__ W2,  // [64,5]
    const float* __restrict__ b2,  // [5]
    float* __restrict__ out,       // [B,5]
    int B)
{
    // xg double buffer: [buf][seq][gate][36] floats (pad 32->36 keeps b128
    // 16B-aligned: 144B row stride; banks (36*gate)%32 = 4*gate%32 -> 2-way
    // aliasing only (free, m136)). 2*16*16*36*4 = 73728 B.
    __shared__ float xgbuf[2][16][16][36];

    const int tidx = threadIdx.x;

#define DOT4S(v, w0_, w1_, w2_, w3_, seed) \
    fmaf((v).x, (w0_), fmaf((v).y, (w1_), fmaf((v).z, (w2_), fmaf((v).w, (w3_), (seed)))))

    if (tidx >= 256) {
        // ---------------- producer waves (4-7) ----------------
        const int pl   = tidx - 256;
        const int seqp = pl >> 4;       // seq within block (0..15)
        const int gp   = pl & 15;       // owned gate column (Keras i,f,g,o)
        const bool isgp = ((gp >> 2) == 2);
        const float k1p = isgp ? (-2.0f * LOG2E) : (-LOG2E);

        float wkp[16];
#pragma unroll
        for (int f = 0; f < 16; ++f) wkp[f] = k1p * Wk[f * 16 + gp];
        const float biasP = k1p * bg[gp];

        // xs[t*4 + k] = x[seq][t][4k..4k+3]
        const float4* xs = reinterpret_cast<const float4*>(
            x + (size_t)(blockIdx.x * 16 + seqp) * TLEN * 16);

#define PDOT(T) \
    ((DOT4S(xs[(T) * 4 + 0], wkp[0], wkp[1], wkp[2], wkp[3], biasP) + \
      DOT4S(xs[(T) * 4 + 1], wkp[4], wkp[5], wkp[6], wkp[7], 0.0f)) + \
     (DOT4S(xs[(T) * 4 + 2], wkp[8], wkp[9], wkp[10], wkp[11], 0.0f) + \
      DOT4S(xs[(T) * 4 + 3], wkp[12], wkp[13], wkp[14], wkp[15], 0.0f)))

#define PRODUCE(C, BF) { \
    const int tb_ = (C) * 32; \
    _Pragma("unroll") \
    for (int t4 = 0; t4 < 8; ++t4) { \
        float4 d_; \
        d_.x = PDOT(tb_ + t4 * 4 + 0); \
        d_.y = PDOT(tb_ + t4 * 4 + 1); \
        d_.z = PDOT(tb_ + t4 * 4 + 2); \
        d_.w = PDOT(tb_ + t4 * 4 + 3); \
        *reinterpret_cast<float4*>(&xgbuf[BF][seqp][gp][t4 * 4]) = d_; \
    } }

        PRODUCE(0, 0);
        __syncthreads();
#pragma clang loop unroll(disable)
        for (int c = 0; c < 16; ++c) {
            if (c + 1 < 16) { PRODUCE(c + 1, (c + 1) & 1); }
            __syncthreads();
        }
        return;   // producers exit; no barriers after this point
    }

    // ---------------- consumer waves (0-3) ----------------
    const int seqc = tidx >> 4;        // seq within block (0..15)
    const int i16  = tidx & 15;
    const int j    = i16 >> 2;         // hidden unit owned by this quad
    const int q    = i16 & 3;          // gate type: 0=i, 1=f, 2=g, 3=o
    const int gate = q * 4 + j;        // column in gates[16]
    const int seq  = blockIdx.x * 16 + seqc;

    const bool is_g = (q == 2);
    const float k1 = is_g ? (-2.0f * LOG2E) : (-LOG2E);
    const float m1c = is_g ? (-4.0f * LOG2E) : 1.0f;
    const float m0c = is_g ? (2.0f * LOG2E) : 0.0f;

    const float wr0 = k1 * Wr[(j ^ 0) * 16 + gate];
    const float wr1 = k1 * Wr[(j ^ 1) * 16 + gate];
    const float wr2 = k1 * Wr[(j ^ 2) * 16 + gate];
    const float wr3 = k1 * Wr[(j ^ 3) * 16 + gate];

    float cs = 0.0f, h = 0.0f;   // cs = -2*log2e * c

// tree-shaped preactivation sum, then the LSTM cell update (verified R8-R13)
#define STEP(XD) { \
    float h1_ = XOR7(XOR3(h));   /* h[j^1] */ \
    float h2_ = XOR8(h);         /* h[j^2] */ \
    float h3_ = XOR8(h1_);       /* h[j^3] */ \
    float preA = fmaf(h, wr0, fmaf(h1_, wr1, (XD))); \
    float preB = fmaf(h2_, wr2, h3_ * wr3); \
    float pre = preA + preB; \
    float r_ = RCPF(1.0f + EXP2F(pre)); \
    float av = fmaf(m1c, r_, m0c); \
    float iv = QB(av, 0); \
    float fv = QB(av, 1); \
    float gv = QB(av, 2); \
    float ov = QB(av, 3); \
    cs = fmaf(fv, cs, iv * gv); \
    float th_ = fmaf(2.0f, RCPF(1.0f + EXP2F(cs)), -1.0f); \
    h = ov * th_; }

    __syncthreads();   // matches producers' post-PRODUCE(0) barrier
#pragma clang loop unroll(disable)
    for (int c = 0; c < 16; ++c) {
        const float* xr = &xgbuf[c & 1][seqc][gate][0];
        float4 xq = *reinterpret_cast<const float4*>(xr);
#pragma unroll
        for (int tg = 0; tg < 8; ++tg) {
            float4 xn;
            if (tg < 7) xn = *reinterpret_cast<const float4*>(xr + (tg + 1) * 4);
            STEP(xq.x);
            STEP(xq.y);
            STEP(xq.z);
            STEP(xq.w);
            xq = xn;
        }
        __syncthreads();
    }

    // ---- MLP head (consumers only; verified R2/R6-R13) ----
    float hA = h;
    float hB = SWZ(h, 4), hC = SWZ(h, 8), hD = SWZ(h, 12);

    float p0 = 0.f, p1 = 0.f, p2 = 0.f, p3 = 0.f, p4 = 0.f;
#pragma unroll
    for (int r = 0; r < 4; ++r) {
        const int u = i16 * 4 + r;            // hidden unit of layer 1
        float acc = b1[u];
        acc = fmaf(hA, W1[(j ^ 0) * 64 + u], acc);
        acc = fmaf(hB, W1[(j ^ 1) * 64 + u], acc);
        acc = fmaf(hC, W1[(j ^ 2) * 64 + u], acc);
        acc = fmaf(hD, W1[(j ^ 3) * 64 + u], acc);
        acc = fmaxf(acc, 0.0f);
        p0 = fmaf(acc, W2[u * 5 + 0], p0);
        p1 = fmaf(acc, W2[u * 5 + 1], p1);
        p2 = fmaf(acc, W2[u * 5 + 2], p2);
        p3 = fmaf(acc, W2[u * 5 + 3], p3);
        p4 = fmaf(acc, W2[u * 5 + 4], p4);
    }
    // butterfly all-reduce across the 16-lane group
    p0 += SWZ(p0, 1); p1 += SWZ(p1, 1); p2 += SWZ(p2, 1); p3 += SWZ(p3, 1); p4 += SWZ(p4, 1);
    p0 += SWZ(p0, 2); p1 += SWZ(p1, 2); p2 += SWZ(p2, 2); p3 += SWZ(p3, 2); p4 += SWZ(p4, 2);
    p0 += SWZ(p0, 4); p1 += SWZ(p1, 4); p2 += SWZ(p2, 4); p3 += SWZ(p3, 4); p4 += SWZ(p4, 4);
    p0 += SWZ(p0, 8); p1 += SWZ(p1, 8); p2 += SWZ(p2, 8); p3 += SWZ(p3, 8); p4 += SWZ(p4, 8);

    p0 += b2[0]; p1 += b2[1]; p2 += b2[2]; p3 += b2[3]; p4 += b2[4];

    float mx = fmaxf(fmaxf(fmaxf(p0, p1), fmaxf(p2, p3)), p4);
    float e0 = EXP2F((p0 - mx) * LOG2E);
    float e1 = EXP2F((p1 - mx) * LOG2E);
    float e2 = EXP2F((p2 - mx) * LOG2E);
    float e3 = EXP2F((p3 - mx) * LOG2E);
    float e4 = EXP2F((p4 - mx) * LOG2E);
    float s = ((e0 + e1) + (e2 + e3)) + e4;
    float rs = RCPF(s);

    if (i16 == 0) {
        float* op = out + (size_t)seq * 5;
        op[0] = e0 * rs; op[1] = e1 * rs; op[2] = e2 * rs;
        op[3] = e3 * rs; op[4] = e4 * rs;
    }
}

extern "C" void kernel_launch(void* const* d_in, const int* in_sizes, int n_in,
                              void* d_out, int out_size, void* d_ws, size_t ws_size,
                              hipStream_t stream) {
    const float* x  = (const float*)d_in[0];
    const float* Wk = (const float*)d_in[1];
    const float* Wr = (const float*)d_in[2];
    const float* bg = (const float*)d_in[3];
    const float* W1 = (const float*)d_in[4];
    const float* b1 = (const float*)d_in[5];
    const float* W2 = (const float*)d_in[6];
    const float* b2 = (const float*)d_in[7];
    float* out = (float*)d_out;

    const int B = in_sizes[0] / (TLEN * 16);   // 4096
    dim3 block(512);                           // 4 consumer + 4 producer waves
    dim3 grid(B / 16);                         // 16 seqs per block
    lstm_mlp_kernel<<<grid, block, 0, stream>>>(x, Wk, Wr, bg, W1, b1, W2, b2, out, B);
}